// Round 9
// baseline (173.909 us; speedup 1.0000x reference)
//
#include <hip/hip_runtime.h>

#define HH 64
#define WW 64
#define S  68          // padded LDS row stride (floats)
#define PH 66          // padded rows (1-px zero frame)
#define NLQ 10
#define NR 8           // rows per thread (512 threads = 8 waves = 2/SIMD)

// One block per image (grid=256 = 1 block/CU). Thread t: column x=t&63, rows
// y0..y0+7. ALLOCATOR-AWARE DESIGN: the backend grants at most ~108 arch
// VGPRs here (proven R2-R8) and demotes the rest to AGPRs at one
// v_accvgpr_read per USE. The old j-outer loop used each of the 90 transition
// weights 8x/step (720 AGPR reads = the 111us plateau). This version loads
// the full 10x3 window (30 regs, shared by all channels) once per step and
// iterates channels OUTER, rows inner: each weight is used once per step
// (<=90 AGPR reads, many free in arch regs), q0 at its irreducible 80 reads.
__global__ __launch_bounds__(512)
__attribute__((amdgpu_waves_per_eu(2, 2)))
void vin_fused(
    const float* __restrict__ X,    // [B,2,64,64]
    const float* __restrict__ Wh,   // [150,2,3,3]
    const float* __restrict__ bh,   // [150]
    const float* __restrict__ Wr,   // [150]
    const float* __restrict__ Wq,   // [10,1,3,3]
    const float* __restrict__ wtr,  // [10,1,3,3] transition
    const float* __restrict__ Wc,   // [4096]
    const float* __restrict__ bc,   // [1]
    float* __restrict__ out)        // [256 critic] ++ [256*40960 q]
{
  __shared__ float vb[2][PH * S];
  __shared__ float rb[PH * S];
  __shared__ float Wef[19];
  __shared__ float Wpart[152];
  __shared__ float Wts[90];
  __shared__ float Wqs[90];
  __shared__ float red[8];

  const int b  = blockIdx.x;
  const int t  = threadIdx.x;
  const int x  = t & 63;
  const int yg = t >> 6;
  const int y0 = yg * NR;
  const int base0 = y0 * S + x;   // top-left of 3x3 window for row y0 (padded)

  // ---- zero LDS (frames must be 0; interiors overwritten) ----
  {
    float* vbf = &vb[0][0];
    for (int i = t; i < 2 * PH * S; i += 512) vbf[i] = 0.f;
    for (int i = t; i < PH * S; i += 512) rb[i] = 0.f;
  }
  __syncthreads();

  // ---- stage X into vb interiors; stage weights; collapse 150-ch conv ----
  const float* Xb = X + (size_t)b * (2 * HH * WW);
  for (int i = t; i < HH * WW; i += 512) {
    const int yy = i >> 6, xx = i & 63;
    vb[0][(yy + 1) * S + xx + 1] = Xb[i];
    vb[1][(yy + 1) * S + xx + 1] = Xb[HH * WW + i];
  }
  if (t < 152) {                       // parallel collapse: 19 outputs x 8 parts
    const int i = t >> 3, part = t & 7;
    float s = 0.f;
    if (i < 18) {
      for (int c = part; c < 150; c += 8) s += Wr[c] * Wh[c * 18 + i];
    } else {
      for (int c = part; c < 150; c += 8) s += Wr[c] * bh[c];
    }
    Wpart[t] = s;
  } else if (t >= 256 && t < 346) {
    Wts[t - 256] = wtr[t - 256];
  } else if (t >= 352 && t < 442) {
    Wqs[t - 352] = Wq[t - 352];
  }
  __syncthreads();
  if (t < 19) {
    float s = 0.f;
#pragma unroll
    for (int k = 0; k < 8; ++k) s += Wpart[t * 8 + k];
    Wef[t] = s;
  }
  __syncthreads();

  // ---- r = conv(X, Weff, pad=1) + beff -> rb ----
  {
    float We[19];
#pragma unroll
    for (int i = 0; i < 19; ++i) We[i] = Wef[i];
#pragma unroll
    for (int j = 0; j < NR; ++j) {
      const int tb = base0 + j * S;
      float s = We[18];
#pragma unroll
      for (int dy = 0; dy < 3; ++dy)
#pragma unroll
        for (int dx = 0; dx < 3; ++dx) {
          const int idx = tb + dy * S + dx;
          s = fmaf(vb[0][idx], We[dy * 3 + dx], s);
          s = fmaf(vb[1][idx], We[9 + dy * 3 + dx], s);
        }
      rb[tb + S + 1] = s;
    }
  }
  __syncthreads();

  // ---- q0 = conv(r, Wq, pad=1) -> q0r regs; v_init = max_l q0 -> vb[0] ----
  float q0r[NR][NLQ];
  {
    float win[NR + 2][3];
#pragma unroll
    for (int rr = 0; rr < NR + 2; ++rr) {
      const int a = base0 + rr * S;
      win[rr][0] = rb[a]; win[rr][1] = rb[a + 1]; win[rr][2] = rb[a + 2];
    }
    float m[NR];
#pragma unroll
    for (int l = 0; l < NLQ; ++l) {
      const float w0 = Wqs[l * 9 + 0], w1 = Wqs[l * 9 + 1], w2 = Wqs[l * 9 + 2];
      const float w3 = Wqs[l * 9 + 3], w4 = Wqs[l * 9 + 4], w5 = Wqs[l * 9 + 5];
      const float w6 = Wqs[l * 9 + 6], w7 = Wqs[l * 9 + 7], w8 = Wqs[l * 9 + 8];
#pragma unroll
      for (int j = 0; j < NR; ++j) {
        float s;
        s = fmaf(w0, win[j][0], 0.f);
        s = fmaf(w1, win[j][1], s);
        s = fmaf(w2, win[j][2], s);
        s = fmaf(w3, win[j + 1][0], s);
        s = fmaf(w4, win[j + 1][1], s);
        s = fmaf(w5, win[j + 1][2], s);
        s = fmaf(w6, win[j + 2][0], s);
        s = fmaf(w7, win[j + 2][1], s);
        s = fmaf(w8, win[j + 2][2], s);
        q0r[j][l] = s;
        m[j] = (l == 0) ? s : fmaxf(m[j], s);
      }
    }
#pragma unroll
    for (int j = 0; j < NR; ++j) vb[0][base0 + (j + 1) * S + 1] = m[j];
  }
  __syncthreads();

  // ---- K-loop: q = q0 + conv(v, w); v = max_ch(q) ----
  float Wt[90];
#pragma unroll
  for (int i = 0; i < 90; ++i) Wt[i] = Wts[i];

  auto step = [&](const float* __restrict__ vin, float* __restrict__ vout) {
    // Full 10x3 window once per step: shared by all 10 channels.
    float win[NR + 2][3];
#pragma unroll
    for (int rr = 0; rr < NR + 2; ++rr) {
      const int a = base0 + rr * S;
      win[rr][0] = vin[a]; win[rr][1] = vin[a + 1]; win[rr][2] = vin[a + 2];
    }
    float m[NR];
    // Channels OUTER: each weight touched once per step (AGPR tax 1x, not 8x).
#pragma unroll
    for (int l = 0; l < NLQ; ++l) {
      const float w0 = Wt[l * 9 + 0], w1 = Wt[l * 9 + 1], w2 = Wt[l * 9 + 2];
      const float w3 = Wt[l * 9 + 3], w4 = Wt[l * 9 + 4], w5 = Wt[l * 9 + 5];
      const float w6 = Wt[l * 9 + 6], w7 = Wt[l * 9 + 7], w8 = Wt[l * 9 + 8];
#pragma unroll
      for (int j = 0; j < NR; ++j) {
        float s = q0r[j][l];
        s = fmaf(w0, win[j][0], s);
        s = fmaf(w1, win[j][1], s);
        s = fmaf(w2, win[j][2], s);
        s = fmaf(w3, win[j + 1][0], s);
        s = fmaf(w4, win[j + 1][1], s);
        s = fmaf(w5, win[j + 1][2], s);
        s = fmaf(w6, win[j + 2][0], s);
        s = fmaf(w7, win[j + 2][1], s);
        s = fmaf(w8, win[j + 2][2], s);
        m[j] = (l == 0) ? s : fmaxf(m[j], s);
      }
    }
#pragma unroll
    for (int j = 0; j < NR; ++j) vout[base0 + (j + 1) * S + 1] = m[j];
    __syncthreads();
  };

#pragma unroll 1
  for (int s2 = 0; s2 < 19; ++s2) { step(vb[0], vb[1]); step(vb[1], vb[0]); }
  step(vb[0], vb[1]);   // it = 38: reads vb[0], writes vb[1]

  // ---- final iteration (it=39): emit q + critic dot ----
  float wcv[NR];
#pragma unroll
  for (int j = 0; j < NR; ++j) wcv[j] = Wc[(y0 + j) * WW + x];

  float* qo = out + 256 + (size_t)b * (NLQ * HH * WW) + y0 * WW + x;
  float acc = 0.f;
  {
    const float* vin = vb[1];
    float win[NR + 2][3];
#pragma unroll
    for (int rr = 0; rr < NR + 2; ++rr) {
      const int a = base0 + rr * S;
      win[rr][0] = vin[a]; win[rr][1] = vin[a + 1]; win[rr][2] = vin[a + 2];
    }
    float m[NR];
#pragma unroll
    for (int l = 0; l < NLQ; ++l) {
      const float w0 = Wt[l * 9 + 0], w1 = Wt[l * 9 + 1], w2 = Wt[l * 9 + 2];
      const float w3 = Wt[l * 9 + 3], w4 = Wt[l * 9 + 4], w5 = Wt[l * 9 + 5];
      const float w6 = Wt[l * 9 + 6], w7 = Wt[l * 9 + 7], w8 = Wt[l * 9 + 8];
#pragma unroll
      for (int j = 0; j < NR; ++j) {
        float s = q0r[j][l];
        s = fmaf(w0, win[j][0], s);
        s = fmaf(w1, win[j][1], s);
        s = fmaf(w2, win[j][2], s);
        s = fmaf(w3, win[j + 1][0], s);
        s = fmaf(w4, win[j + 1][1], s);
        s = fmaf(w5, win[j + 1][2], s);
        s = fmaf(w6, win[j + 2][0], s);
        s = fmaf(w7, win[j + 2][1], s);
        s = fmaf(w8, win[j + 2][2], s);
        qo[l * (HH * WW) + j * WW] = s;
        m[j] = (l == 0) ? s : fmaxf(m[j], s);
      }
    }
#pragma unroll
    for (int j = 0; j < NR; ++j) acc = fmaf(m[j], wcv[j], acc);
  }

  // ---- block-reduce critic ----
#pragma unroll
  for (int off = 32; off > 0; off >>= 1) acc += __shfl_down(acc, off);
  if (x == 0) red[yg] = acc;
  __syncthreads();
  if (t == 0) {
    float s = bc[0];
#pragma unroll
    for (int i = 0; i < 8; ++i) s += red[i];
    out[b] = s;
  }
}

extern "C" void kernel_launch(void* const* d_in, const int* in_sizes, int n_in,
                              void* d_out, int out_size, void* d_ws, size_t ws_size,
                              hipStream_t stream) {
  (void)n_in; (void)out_size; (void)d_ws; (void)ws_size;
  const float* X   = (const float*)d_in[0];
  const float* Wh  = (const float*)d_in[1];
  const float* bh  = (const float*)d_in[2];
  const float* Wr  = (const float*)d_in[3];
  const float* Wq  = (const float*)d_in[4];
  const float* wtr = (const float*)d_in[5];
  const float* Wc  = (const float*)d_in[6];
  const float* bc  = (const float*)d_in[7];
  float* out = (float*)d_out;

  const int B = in_sizes[0] / (2 * HH * WW);   // 256
  vin_fused<<<B, 512, 0, stream>>>(X, Wh, bh, Wr, Wq, wtr, Wc, bc, out);
}